// Round 6
// baseline (924.935 us; speedup 1.0000x reference)
//
#include <hip/hip_runtime.h>
#include <hip/hip_fp16.h>
#include <stdint.h>

#define AS1 __attribute__((address_space(1)))
#define AS3 __attribute__((address_space(3)))

typedef unsigned short u16;
typedef __attribute__((ext_vector_type(8))) short short8;
typedef __attribute__((ext_vector_type(4))) float f32x4;

#define LOG2PI_F 1.8378770664093453f

// problem constants
#define BQ   16
#define TQ   256
#define DQ   512
#define LQ   51
#define L2Q  2601
#define KQ   1536     // 3*512 (split-bf16: [xh, xl, xh] . [Wh; Wh; Wl])
#define NCOL   15759
#define NPAD   15872  // 124*128
// permuted column layout (baked into B^T row order):
//   col < 15606 : 6*ij + {0:tw, 1:m0, 2:m1, 3:d0, 4:ofac, 5:d1}
//   s-blocks    : sw @ SB0+j, smu @ SB1+j, svar @ SB2+j   (j<51)
//   rest: zero pad
#define NSTR 15606
#define SB0  15616
#define SB1  15680
#define SB2  15744

__device__ __forceinline__ u16 f2bf(float f) {
  uint32_t u = __float_as_uint(f);
  u += 0x7fffu + ((u >> 16) & 1u);   // RNE
  return (u16)(u >> 16);
}
__device__ __forceinline__ float bf2f(u16 h) {
  return __uint_as_float((uint32_t)h << 16);
}
__device__ __forceinline__ float frcp(float x) { return __builtin_amdgcn_rcpf(x); }
__device__ __forceinline__ float flog(float x) { return __builtin_amdgcn_logf(x) * 0.6931471805599453f; }

// ---------------------------------------------------------------- build A
__global__ __launch_bounds__(256) void build_a_kernel(const float* __restrict__ x,
                                                      u16* __restrict__ A) {
  int idx = blockIdx.x * 256 + threadIdx.x;   // exactly 4096*512
  int m = idx >> 9;
  int k = idx & 511;
  float v = x[idx];
  u16 h = f2bf(v);
  u16 l = f2bf(v - bf2f(h));
  u16* row = A + (size_t)m * KQ;
  row[k] = h;
  row[DQ + k] = l;
  row[2 * DQ + k] = h;
}

// ---------------------------------------------------------------- build B^T
// k-parallel: blockIdx.y picks an 8-wide k-slab (64 slabs), thread = column n.
__global__ __launch_bounds__(256) void build_b_kernel(
    const float* __restrict__ Ws_w, const float* __restrict__ Ws_mu,
    const float* __restrict__ Ws_var, const float* __restrict__ Wt_w,
    const float* __restrict__ Wt_mu, const float* __restrict__ Wt_var,
    u16* __restrict__ BT) {
  int n = blockIdx.x * 256 + threadIdx.x;
  if (n >= NPAD) return;
  const float* src = nullptr;
  int c0 = 0, stride = 0, two = 0;
  if (n < NSTR) {
    int ij = (int)((unsigned)n / 6u);
    int r = n - 6 * ij;
    switch (r) {
      case 0: src = Wt_w;   stride = L2Q;     c0 = ij;         break;
      case 1: src = Wt_mu;  stride = 2 * L2Q; c0 = 2 * ij;     break;
      case 2: src = Wt_mu;  stride = 2 * L2Q; c0 = 2 * ij + 1; break;
      case 3: src = Wt_var; stride = 4 * L2Q; c0 = 4 * ij;     break;
      case 4: src = Wt_var; stride = 4 * L2Q; c0 = 4 * ij + 1; two = 1; break;
      default: src = Wt_var; stride = 4 * L2Q; c0 = 4 * ij + 3; break;
    }
  } else if (n >= SB0 && n < SB0 + LQ) { src = Ws_w;   stride = LQ; c0 = n - SB0; }
  else if (n >= SB1 && n < SB1 + LQ)   { src = Ws_mu;  stride = LQ; c0 = n - SB1; }
  else if (n >= SB2 && n < SB2 + LQ)   { src = Ws_var; stride = LQ; c0 = n - SB2; }
  u16* row = BT + (size_t)n * KQ;
  int kb = blockIdx.y * 8;
  union { u16 u[8]; uint4 v; } H, L;
#pragma unroll
  for (int t = 0; t < 8; ++t) {
    float w = 0.f;
    if (src) {
      const float* p = src + (size_t)(kb + t) * stride + c0;
      w = p[0];
      if (two) w += p[1];
    }
    u16 h = f2bf(w);
    H.u[t] = h;
    L.u[t] = f2bf(w - bf2f(h));
  }
  *(uint4*)(row + kb) = H.v;
  *(uint4*)(row + DQ + kb) = H.v;
  *(uint4*)(row + 2 * DQ + kb) = L.v;
}

// ---------------------------------------------------------------- epilogue transform
__device__ __forceinline__ float xform(int col, float v,
    const float* __restrict__ bs_w, const float* __restrict__ bs_mu,
    const float* __restrict__ bs_var, const float* __restrict__ bt_w,
    const float* __restrict__ bt_mu, const float* __restrict__ bt_var) {
  if (col < NSTR) {
    int ij = (int)((unsigned)col / 6u);
    int r = col - 6 * ij;
    if (r == 0) return v + bt_w[ij];
    if (r == 1) return v + bt_mu[2 * ij];
    if (r == 2) return v + bt_mu[2 * ij + 1];
    if (r == 4) {
      float u = v + bt_var[4 * ij + 1] + bt_var[4 * ij + 2];
      u = fminf(fmaxf(u, -20.f), 20.f);
      float ex = __expf(u);               // tanh(u/2) = (e^u-1)/(e^u+1)
      return 0.9f * (ex - 1.f) / (ex + 1.f);
    }
    float u = v + bt_var[4 * ij + (r == 3 ? 0 : 3)];
    u = fminf(fmaxf(u, -1.f), 1.f);
    return __expf(u);
  }
  if (col >= SB0 && col < SB0 + LQ) return v + bs_w[col - SB0];
  if (col >= SB1 && col < SB1 + LQ) return v + bs_mu[col - SB1];
  if (col >= SB2 && col < SB2 + LQ) {
    float u = v + bs_var[col - SB2];
    u = fminf(fmaxf(u, -1.f), 1.f);
    return __expf(u);
  }
  return v;   // pad (exactly 0)
}

// ---------------------------------------------------------------- GEMM (m97-style)
// XCD-swizzled 1-D grid: lin -> (xcd = lin&7, s = lin>>3),
// mtile = s & (nmt-1), ntile = (s>>lg_nmt)*8 + xcd.  One ntile's mtile cohort
// runs consecutively on ONE XCD -> its 393KB B-slice stays L2-hot.
__global__ __launch_bounds__(256, 2) void gemm_kernel(
    const u16* __restrict__ A, const u16* __restrict__ BT,
    __half* __restrict__ C,
    const float* __restrict__ bs_w, const float* __restrict__ bs_mu,
    const float* __restrict__ bs_var, const float* __restrict__ bt_w,
    const float* __restrict__ bt_mu, const float* __restrict__ bt_var,
    int t0, int lgTC, int lg_nmt) {
  const int lin = blockIdx.x;
  const int xcd = lin & 7;
  const int s = lin >> 3;
  const int mtile = s & ((1 << lg_nmt) - 1);
  const int ntile = ((s >> lg_nmt) << 3) + xcd;
  if (ntile >= 124) return;

  __shared__ uint4 sA[1024];   // 16B units: [kc(0..7)][row(0..127)]
  __shared__ uint4 sB[1024];   // 16B units: [kc(0..7)][n(0..127)]
  const int tid = threadIdx.x;
  const int lane = tid & 63;
  const int wave = tid >> 6;
  const int wm = (wave >> 1) * 64;
  const int wn = (wave & 1) * 64;
  const int q4 = lane >> 4;
  const int c16 = lane & 15;
  const int tcm1 = (1 << lgTC) - 1;

  uint32_t aoff[4], boff[4];
#pragma unroll
  for (int ss = 0; ss < 4; ++ss) {
    int jj = wave * 4 + ss;                    // staging instr 0..15
    int kc = jj >> 1;
    int r = ((jj & 1) << 6) + lane;            // tile row / tile col
    int mloc = mtile * 128 + r;
    int gr = ((mloc >> lgTC) << 8) + t0 + (mloc & tcm1);  // global x-row = b*256 + t
    aoff[ss] = (uint32_t)gr * KQ + kc * 8;
    int n = ntile * 128 + r;
    boff[ss] = (uint32_t)n * KQ + kc * 8;
  }

  f32x4 acc[4][4];
#pragma unroll
  for (int a_ = 0; a_ < 4; ++a_)
#pragma unroll
    for (int b_ = 0; b_ < 4; ++b_) acc[a_][b_] = (f32x4){0.f, 0.f, 0.f, 0.f};

  AS3 uint4* sA3 = (AS3 uint4*)sA;
  AS3 uint4* sB3 = (AS3 uint4*)sB;

  for (int k0 = 0; k0 < KQ; k0 += 64) {
#pragma unroll
    for (int ss = 0; ss < 4; ++ss) {
      int jj = wave * 4 + ss;
      __builtin_amdgcn_global_load_lds((const AS1 void*)(A + aoff[ss] + k0),
                                       (AS3 void*)(sA3 + jj * 64), 16, 0, 0);
      __builtin_amdgcn_global_load_lds((const AS1 void*)(BT + boff[ss] + k0),
                                       (AS3 void*)(sB3 + jj * 64), 16, 0, 0);
    }
    __syncthreads();
#pragma unroll
    for (int ks = 0; ks < 2; ++ks) {
      int kc = ks * 4 + q4;
      short8 af[4], bfv[4];
#pragma unroll
      for (int f = 0; f < 4; ++f) {
        af[f]  = *(const short8*)&sA[kc * 128 + wm + f * 16 + c16];
        bfv[f] = *(const short8*)&sB[kc * 128 + wn + f * 16 + c16];
      }
#pragma unroll
      for (int fr = 0; fr < 4; ++fr)
#pragma unroll
        for (int fc = 0; fc < 4; ++fc)
          acc[fr][fc] = __builtin_amdgcn_mfma_f32_16x16x32_bf16(af[fr], bfv[fc],
                                                                acc[fr][fc], 0, 0, 0);
    }
    __syncthreads();
  }

  // epilogue: C/D layout col=lane&15, row=q4*4+reg; contiguous fp16 writes
#pragma unroll
  for (int fc = 0; fc < 4; ++fc) {
    int col = ntile * 128 + wn + fc * 16 + c16;
#pragma unroll
    for (int fr = 0; fr < 4; ++fr) {
      int grow = mtile * 128 + wm + fr * 16 + q4 * 4;   // chunk-local row b*TC+tloc
#pragma unroll
      for (int i = 0; i < 4; ++i) {
        float vv = xform(col, acc[fr][fc][i], bs_w, bs_mu, bs_var, bt_w, bt_mu, bt_var);
        C[(size_t)(grow + i) * NPAD + col] = __float2half(vv);
      }
    }
  }
}

// ---------------------------------------------------------------- scan
struct Vals { float sw, smu, svar, tw, m0, m1, d0, ofac, d1; };
struct Raw  { uint32_t w0, w1, w2; u16 s0, s1, s2; };

__device__ __forceinline__ Raw ldraw(const u16* __restrict__ rowp, int ij, int j) {
  Raw r;
  const u16* q = rowp + 6 * ij;          // byte offset 12*ij: 4B-aligned
  r.w0 = *(const uint32_t*)q;            // tw, m0
  r.w1 = *(const uint32_t*)(q + 2);      // m1, d0
  r.w2 = *(const uint32_t*)(q + 4);      // ofac, d1
  r.s0 = rowp[SB0 + j];
  r.s1 = rowp[SB1 + j];
  r.s2 = rowp[SB2 + j];
  return r;
}

__device__ __forceinline__ float h2f(u16 bits) {
  union { u16 u; __half h; } cv; cv.u = bits;
  return __half2float(cv.h);
}

__device__ __forceinline__ Vals cvtvals(const Raw& r) {
  Vals v;
  float2 a = __half22float2(*(const __half2*)&r.w0);
  float2 b = __half22float2(*(const __half2*)&r.w1);
  float2 c = __half22float2(*(const __half2*)&r.w2);
  v.tw = a.x; v.m0 = a.y; v.m1 = b.x; v.d0 = b.y; v.ofac = c.x; v.d1 = c.y;
  v.sw = h2f(r.s0); v.smu = h2f(r.s1); v.svar = h2f(r.s2);
  return v;
}

template <bool CHILD>
__device__ __forceinline__ float merge2(const Vals& v, float nmu, float nvar,
                                        float& mu_n, float& var_n) {
  float off = v.ofac * __builtin_amdgcn_sqrtf(v.d0 * v.d1);
  float det = fmaf(v.d0, v.d1, -off * off);
  float inv = frcp(det);
  float a = v.d1 * inv, bo = -off * inv, d = v.d0 * inv;
  float e0 = a * v.m0 + bo * v.m1;
  float e1 = bo * v.m0 + d * v.m1;
  float quad1 = e0 * e0 * v.d0 + 2.f * e0 * e1 * off + e1 * e1 * v.d1;
  float zeta1 = -0.5f * (2.f * LOG2PI_F + flog(det) + quad1);
  float l2 = frcp(nvar);
  float eta2 = nmu * l2;
  float zeta2 = -0.5f * (LOG2PI_F + flog(nvar) + nmu * eta2);
  float den, keep, es, la;
  if (CHILD) { den = d + l2; keep = e0; es = e1 + eta2; }
  else       { den = a + l2; keep = e1; es = e0 + eta2; }
  float rden = frcp(den);
  if (CHILD) la = a - bo * bo * rden;
  else       la = d - bo * bo * rden;
  float etan = keep - bo * rden * es;
  var_n = frcp(la);
  mu_n = var_n * etan;
  float zm = -0.5f * (LOG2PI_F - flog(den) + es * es * rden);
  float zn = -0.5f * (LOG2PI_F - flog(la) + etan * etan * var_n);
  return zeta1 + zeta2 - zm - zn;
}

__device__ __forceinline__ void step_fn(const Vals& cur, float& mu_p, float& var_p,
                                        float* __restrict__ outp) {
  float vsum = var_p + cur.svar;
  float rv = frcp(vsum);
  float logv = flog(vsum);
  float dmu = mu_p - cur.smu;
  float sc = -0.5f * (LOG2PI_F + logv + dmu * dmu * rv);
  float mu_c = (mu_p * cur.svar + cur.smu * var_p) * rv;
  float var_c = vsum - 0.5f * logv;
  float sp = merge2<false>(cur, mu_c, var_c, mu_p, var_p);
  *outp = sc + sp + cur.tw + cur.sw;
}

#define PF 8   // prefetch ring depth — statically indexed (registers guaranteed)

__global__ __launch_bounds__(256) void scan_kernel(
    const u16* __restrict__ Ch, float* __restrict__ out, float* __restrict__ carry,
    int t0, int TC, int isFirst, int isLast) {
  int ij = blockIdx.y * 256 + threadIdx.x;
  if (ij >= L2Q) return;
  int b = blockIdx.x;
  int j = ij % 51;
  const u16* base = Ch + (size_t)b * TC * NPAD;   // chunk-local rows
  float* outb = out + (size_t)b * TQ * L2Q + ij;
  float mu_p, var_p;
  int tfirst;
  if (isFirst) {
    Raw r0 = ldraw(base, ij, j);
    Raw r1 = ldraw(base + NPAD, ij, j);
    Vals v0 = cvtvals(r0);
    Vals v1 = cvtvals(r1);
    float mu_c, var_c;
    float sc0 = merge2<true>(v0, v0.smu, v0.svar, mu_c, var_c);
    float sp0 = merge2<false>(v1, mu_c, var_c, mu_p, var_p);
    outb[0] = sc0 + sp0 + v0.tw + v0.sw;
    tfirst = 1;
  } else {
    mu_p = carry[b * L2Q + ij];
    var_p = carry[BQ * L2Q + b * L2Q + ij];
    tfirst = t0;
  }
  int tend = t0 + TC;
  Raw ring[PF];
#pragma unroll
  for (int p = 0; p < PF; ++p) {
    int t = tfirst + p;
    if (t < tend) ring[p] = ldraw(base + (size_t)(t - t0) * NPAD, ij, j);
  }
  int t = tfirst;
#pragma unroll 1
  while (t + PF <= tend) {
#pragma unroll
    for (int p = 0; p < PF; ++p) {
      Raw cr = ring[p];
      int tp = t + PF;
      if (tp < tend) ring[p] = ldraw(base + (size_t)(tp - t0) * NPAD, ij, j);
      Vals cur = cvtvals(cr);
      step_fn(cur, mu_p, var_p, outb + (size_t)t * L2Q);
      ++t;
    }
  }
#pragma unroll
  for (int p = 0; p < PF; ++p) {
    if (t < tend) {
      Vals cur = cvtvals(ring[p]);
      step_fn(cur, mu_p, var_p, outb + (size_t)t * L2Q);
      ++t;
    }
  }
  if (!isLast) {
    carry[b * L2Q + ij] = mu_p;
    carry[BQ * L2Q + b * L2Q + ij] = var_p;
  }
}

// ---------------------------------------------------------------- launch
extern "C" void kernel_launch(void* const* d_in, const int* in_sizes, int n_in,
                              void* d_out, int out_size, void* d_ws, size_t ws_size,
                              hipStream_t stream) {
  (void)in_sizes; (void)n_in; (void)out_size;
  const float* x      = (const float*)d_in[0];
  const float* Ws_w   = (const float*)d_in[1];
  const float* bs_w   = (const float*)d_in[2];
  const float* Ws_mu  = (const float*)d_in[3];
  const float* bs_mu  = (const float*)d_in[4];
  const float* Ws_var = (const float*)d_in[5];
  const float* bs_var = (const float*)d_in[6];
  const float* Wt_w   = (const float*)d_in[7];
  const float* bt_w   = (const float*)d_in[8];
  const float* Wt_mu  = (const float*)d_in[9];
  const float* bt_mu  = (const float*)d_in[10];
  const float* Wt_var = (const float*)d_in[11];
  const float* bt_var = (const float*)d_in[12];
  float* out = (float*)d_out;

  char* ws = (char*)d_ws;
  const size_t szA = (size_t)4096 * KQ * 2;          // 12,582,912 (256-aligned)
  const size_t szB = (size_t)NPAD * KQ * 2;          // 48,758,784 (256-aligned)
  const size_t szCar = ((size_t)BQ * L2Q * 2 * 4 + 255) & ~(size_t)255;
  u16* Abf = (u16*)ws;
  u16* BTb = (u16*)(ws + szA);
  float* carry = (float*)(ws + szA + szB);
  size_t off0 = szA + szB + szCar;

  // chunk T so the fp16 C buffer fits in ws (TC=256 needs ~192 MB total)
  int TC = 256;
  while (TC > 8 && off0 + (size_t)BQ * TC * NPAD * 2 > ws_size) TC >>= 1;
  __half* Ch = (__half*)(ws + off0);
  int lgTC = 31 - __builtin_clz((unsigned)TC);
  int nch = TQ / TC;
  int nmt = (BQ * TC) / 128;                 // mtiles per chunk (power of 2)
  int lg_nmt = 31 - __builtin_clz((unsigned)nmt);

  build_a_kernel<<<dim3((4096 * 512) / 256), dim3(256), 0, stream>>>(x, Abf);
  build_b_kernel<<<dim3(NPAD / 256, DQ / 8), dim3(256), 0, stream>>>(
      Ws_w, Ws_mu, Ws_var, Wt_w, Wt_mu, Wt_var, BTb);
  for (int c = 0; c < nch; ++c) {
    int t0 = c * TC;
    gemm_kernel<<<dim3(128 * nmt), dim3(256), 0, stream>>>(
        Abf, BTb, Ch, bs_w, bs_mu, bs_var, bt_w, bt_mu, bt_var, t0, lgTC, lg_nmt);
    scan_kernel<<<dim3(BQ, (L2Q + 255) / 256), dim3(256), 0, stream>>>(
        (const u16*)Ch, out, carry, t0, TC, c == 0 ? 1 : 0, c == nch - 1 ? 1 : 0);
  }
}

// Round 7
// 686.173 us; speedup vs baseline: 1.3480x; 1.3480x over previous
//
#include <hip/hip_runtime.h>
#include <hip/hip_fp16.h>
#include <stdint.h>

#define AS1 __attribute__((address_space(1)))
#define AS3 __attribute__((address_space(3)))

typedef unsigned short u16;
typedef __attribute__((ext_vector_type(8))) short short8;
typedef __attribute__((ext_vector_type(4))) float f32x4;

#define LOG2PI_F 1.8378770664093453f

// problem constants
#define BQ   16
#define TQ   256
#define DQ   512
#define LQ   51
#define L2Q  2601
#define KQ   1536     // 3*512 (split-bf16: [xh, xl, xh] . [Wh; Wh; Wl])
#define NCOL   15759
#define NPAD   15872  // 124*128
// tiled operand layout (= LDS staging order): [tile][c8(0..191)][row(0..127)][8 u16]
//   c8 = k'/8 (16B chunk), tile = 128 rows; tile size = 196608 u16 = 24576 uint4
#define TILE_U16  196608
#define TILE_U4   24576
// permuted column layout (baked into B^T row order):
//   col < 15606 : 6*ij + {0:tw, 1:m0, 2:m1, 3:d0, 4:ofac, 5:d1}
//   s-blocks    : sw @ SB0+j, smu @ SB1+j, svar @ SB2+j   (j<51)
#define NSTR 15606
#define SB0  15616
#define SB1  15680
#define SB2  15744

__device__ __forceinline__ u16 f2bf(float f) {
  uint32_t u = __float_as_uint(f);
  u += 0x7fffu + ((u >> 16) & 1u);   // RNE
  return (u16)(u >> 16);
}
__device__ __forceinline__ float bf2f(u16 h) {
  return __uint_as_float((uint32_t)h << 16);
}
__device__ __forceinline__ float frcp(float x) { return __builtin_amdgcn_rcpf(x); }
__device__ __forceinline__ float flog(float x) { return __builtin_amdgcn_logf(x) * 0.6931471805599453f; }

// ---------------------------------------------------------------- build A (tiled)
__global__ __launch_bounds__(256) void build_a_kernel(const float* __restrict__ x,
                                                      u16* __restrict__ A,
                                                      int TC, int lgTC, int nmt) {
  int idx = blockIdx.x * 256 + threadIdx.x;   // exactly 4096*512
  int m = idx >> 9;
  int k = idx & 511;
  float v = x[idx];
  u16 h = f2bf(v);
  u16 l = f2bf(v - bf2f(h));
  int b = m >> 8, t = m & 255;
  int c = t >> lgTC;                 // chunk
  int tloc = t & (TC - 1);
  int mloc = b * TC + tloc;          // chunk-local row
  int mt = mloc >> 7, r = mloc & 127;
  u16* tile = A + (size_t)(c * nmt + mt) * TILE_U16 + r * 8;
  // k' positions: k (xh), 512+k (xl), 1024+k (xh)
  int c8 = k >> 3, e = k & 7;
  tile[(size_t)c8 * 1024 + e] = h;
  tile[(size_t)(64 + c8) * 1024 + e] = l;
  tile[(size_t)(128 + c8) * 1024 + e] = h;
}

// ---------------------------------------------------------------- build B^T (tiled)
// k-parallel: blockIdx.y picks an 8-wide k-slab (64 slabs), thread = column n.
__global__ __launch_bounds__(256) void build_b_kernel(
    const float* __restrict__ Ws_w, const float* __restrict__ Ws_mu,
    const float* __restrict__ Ws_var, const float* __restrict__ Wt_w,
    const float* __restrict__ Wt_mu, const float* __restrict__ Wt_var,
    u16* __restrict__ BT) {
  int n = blockIdx.x * 256 + threadIdx.x;
  if (n >= NPAD) return;
  const float* src = nullptr;
  int c0 = 0, stride = 0, two = 0;
  if (n < NSTR) {
    int ij = (int)((unsigned)n / 6u);
    int r = n - 6 * ij;
    switch (r) {
      case 0: src = Wt_w;   stride = L2Q;     c0 = ij;         break;
      case 1: src = Wt_mu;  stride = 2 * L2Q; c0 = 2 * ij;     break;
      case 2: src = Wt_mu;  stride = 2 * L2Q; c0 = 2 * ij + 1; break;
      case 3: src = Wt_var; stride = 4 * L2Q; c0 = 4 * ij;     break;
      case 4: src = Wt_var; stride = 4 * L2Q; c0 = 4 * ij + 1; two = 1; break;
      default: src = Wt_var; stride = 4 * L2Q; c0 = 4 * ij + 3; break;
    }
  } else if (n >= SB0 && n < SB0 + LQ) { src = Ws_w;   stride = LQ; c0 = n - SB0; }
  else if (n >= SB1 && n < SB1 + LQ)   { src = Ws_mu;  stride = LQ; c0 = n - SB1; }
  else if (n >= SB2 && n < SB2 + LQ)   { src = Ws_var; stride = LQ; c0 = n - SB2; }
  int kb = blockIdx.y * 8;
  union { u16 u[8]; uint4 v; } H, L;
#pragma unroll
  for (int t = 0; t < 8; ++t) {
    float w = 0.f;
    if (src) {
      const float* p = src + (size_t)(kb + t) * stride + c0;
      w = p[0];
      if (two) w += p[1];
    }
    u16 h = f2bf(w);
    H.u[t] = h;
    L.u[t] = f2bf(w - bf2f(h));
  }
  int nt = n >> 7, col = n & 127;
  uint4* tb = (uint4*)BT + (size_t)nt * TILE_U4 + col;
  int c8 = kb >> 3;                              // 0..63
  tb[(size_t)c8 * 128] = H.v;                    // region k' in [0,512)
  tb[(size_t)(64 + c8) * 128] = H.v;             // region [512,1024)
  tb[(size_t)(128 + c8) * 128] = L.v;            // region [1024,1536)
}

// ---------------------------------------------------------------- epilogue transform
__device__ __forceinline__ float xform(int col, float v,
    const float* __restrict__ bs_w, const float* __restrict__ bs_mu,
    const float* __restrict__ bs_var, const float* __restrict__ bt_w,
    const float* __restrict__ bt_mu, const float* __restrict__ bt_var) {
  if (col < NSTR) {
    int ij = (int)((unsigned)col / 6u);
    int r = col - 6 * ij;
    if (r == 0) return v + bt_w[ij];
    if (r == 1) return v + bt_mu[2 * ij];
    if (r == 2) return v + bt_mu[2 * ij + 1];
    if (r == 4) {
      float u = v + bt_var[4 * ij + 1] + bt_var[4 * ij + 2];
      u = fminf(fmaxf(u, -20.f), 20.f);
      float ex = __expf(u);               // tanh(u/2) = (e^u-1)/(e^u+1)
      return 0.9f * (ex - 1.f) / (ex + 1.f);
    }
    float u = v + bt_var[4 * ij + (r == 3 ? 0 : 3)];
    u = fminf(fmaxf(u, -1.f), 1.f);
    return __expf(u);
  }
  if (col >= SB0 && col < SB0 + LQ) return v + bs_w[col - SB0];
  if (col >= SB1 && col < SB1 + LQ) return v + bs_mu[col - SB1];
  if (col >= SB2 && col < SB2 + LQ) {
    float u = v + bs_var[col - SB2];
    u = fminf(fmaxf(u, -1.f), 1.f);
    return __expf(u);
  }
  return v;   // pad (exactly 0)
}

// ---------------------------------------------------------------- GEMM (m97-style)
// Operands pre-tiled in LDS order -> staging is 32 unit-stride 1KB bursts/iter.
// XCD-swizzled 1-D grid keeps one ntile's mtile cohort on one XCD (B L2-hot).
__global__ __launch_bounds__(256, 2) void gemm_kernel(
    const u16* __restrict__ A, const u16* __restrict__ BT,
    __half* __restrict__ C,
    const float* __restrict__ bs_w, const float* __restrict__ bs_mu,
    const float* __restrict__ bs_var, const float* __restrict__ bt_w,
    const float* __restrict__ bt_mu, const float* __restrict__ bt_var,
    int tile0, int lg_nmt) {
  const int lin = blockIdx.x;
  const int xcd = lin & 7;
  const int s = lin >> 3;
  const int mtile = s & ((1 << lg_nmt) - 1);
  const int ntile = ((s >> lg_nmt) << 3) + xcd;
  if (ntile >= 124) return;

  __shared__ uint4 sA[1024];   // 16B units: [kc(0..7)][row(0..127)]
  __shared__ uint4 sB[1024];
  const int tid = threadIdx.x;
  const int lane = tid & 63;
  const int wave = tid >> 6;
  const int wm = (wave >> 1) * 64;
  const int wn = (wave & 1) * 64;
  const int q4 = lane >> 4;
  const int c16 = lane & 15;

  const uint4* At = (const uint4*)A + (size_t)(tile0 + mtile) * TILE_U4;
  const uint4* Bt = (const uint4*)BT + (size_t)ntile * TILE_U4;

  f32x4 acc[4][4];
#pragma unroll
  for (int a_ = 0; a_ < 4; ++a_)
#pragma unroll
    for (int b_ = 0; b_ < 4; ++b_) acc[a_][b_] = (f32x4){0.f, 0.f, 0.f, 0.f};

  AS3 uint4* sA3 = (AS3 uint4*)sA;
  AS3 uint4* sB3 = (AS3 uint4*)sB;

  for (int kwin = 0; kwin < 24; ++kwin) {
    const uint4* wa = At + kwin * 1024;
    const uint4* wb = Bt + kwin * 1024;
#pragma unroll
    for (int ss = 0; ss < 4; ++ss) {
      int jj = wave * 4 + ss;                 // covers uint4 [jj*64, jj*64+64)
      __builtin_amdgcn_global_load_lds((const AS1 void*)(wa + jj * 64 + lane),
                                       (AS3 void*)(sA3 + jj * 64), 16, 0, 0);
      __builtin_amdgcn_global_load_lds((const AS1 void*)(wb + jj * 64 + lane),
                                       (AS3 void*)(sB3 + jj * 64), 16, 0, 0);
    }
    __syncthreads();
#pragma unroll
    for (int ks = 0; ks < 2; ++ks) {
      int kc = ks * 4 + q4;
      short8 af[4], bfv[4];
#pragma unroll
      for (int f = 0; f < 4; ++f) {
        af[f]  = *(const short8*)&sA[kc * 128 + wm + f * 16 + c16];
        bfv[f] = *(const short8*)&sB[kc * 128 + wn + f * 16 + c16];
      }
#pragma unroll
      for (int fr = 0; fr < 4; ++fr)
#pragma unroll
        for (int fc = 0; fc < 4; ++fc)
          acc[fr][fc] = __builtin_amdgcn_mfma_f32_16x16x32_bf16(af[fr], bfv[fc],
                                                                acc[fr][fc], 0, 0, 0);
    }
    __syncthreads();
  }

  // epilogue: C/D layout col=lane&15, row=q4*4+reg; contiguous fp16 writes
#pragma unroll
  for (int fc = 0; fc < 4; ++fc) {
    int col = ntile * 128 + wn + fc * 16 + c16;
#pragma unroll
    for (int fr = 0; fr < 4; ++fr) {
      int grow = mtile * 128 + wm + fr * 16 + q4 * 4;   // chunk-local row b*TC+tloc
#pragma unroll
      for (int i = 0; i < 4; ++i) {
        float vv = xform(col, acc[fr][fc][i], bs_w, bs_mu, bs_var, bt_w, bt_mu, bt_var);
        C[(size_t)(grow + i) * NPAD + col] = __float2half(vv);
      }
    }
  }
}

// ---------------------------------------------------------------- scan
struct Vals { float sw, smu, svar, tw, m0, m1, d0, ofac, d1; };
struct Raw  { uint32_t w0, w1, w2; u16 s0, s1, s2; };

__device__ __forceinline__ Raw ldraw(const u16* __restrict__ rowp, int ij, int j) {
  Raw r;
  const u16* q = rowp + 6 * ij;          // byte offset 12*ij: 4B-aligned
  r.w0 = *(const uint32_t*)q;            // tw, m0
  r.w1 = *(const uint32_t*)(q + 2);      // m1, d0
  r.w2 = *(const uint32_t*)(q + 4);      // ofac, d1
  r.s0 = rowp[SB0 + j];
  r.s1 = rowp[SB1 + j];
  r.s2 = rowp[SB2 + j];
  return r;
}

__device__ __forceinline__ float h2f(u16 bits) {
  union { u16 u; __half h; } cv; cv.u = bits;
  return __half2float(cv.h);
}

__device__ __forceinline__ Vals cvtvals(const Raw& r) {
  Vals v;
  float2 a = __half22float2(*(const __half2*)&r.w0);
  float2 b = __half22float2(*(const __half2*)&r.w1);
  float2 c = __half22float2(*(const __half2*)&r.w2);
  v.tw = a.x; v.m0 = a.y; v.m1 = b.x; v.d0 = b.y; v.ofac = c.x; v.d1 = c.y;
  v.sw = h2f(r.s0); v.smu = h2f(r.s1); v.svar = h2f(r.s2);
  return v;
}

template <bool CHILD>
__device__ __forceinline__ float merge2(const Vals& v, float nmu, float nvar,
                                        float& mu_n, float& var_n) {
  float off = v.ofac * __builtin_amdgcn_sqrtf(v.d0 * v.d1);
  float det = fmaf(v.d0, v.d1, -off * off);
  float inv = frcp(det);
  float a = v.d1 * inv, bo = -off * inv, d = v.d0 * inv;
  float e0 = a * v.m0 + bo * v.m1;
  float e1 = bo * v.m0 + d * v.m1;
  float quad1 = e0 * e0 * v.d0 + 2.f * e0 * e1 * off + e1 * e1 * v.d1;
  float zeta1 = -0.5f * (2.f * LOG2PI_F + flog(det) + quad1);
  float l2 = frcp(nvar);
  float eta2 = nmu * l2;
  float zeta2 = -0.5f * (LOG2PI_F + flog(nvar) + nmu * eta2);
  float den, keep, es, la;
  if (CHILD) { den = d + l2; keep = e0; es = e1 + eta2; }
  else       { den = a + l2; keep = e1; es = e0 + eta2; }
  float rden = frcp(den);
  if (CHILD) la = a - bo * bo * rden;
  else       la = d - bo * bo * rden;
  float etan = keep - bo * rden * es;
  var_n = frcp(la);
  mu_n = var_n * etan;
  float zm = -0.5f * (LOG2PI_F - flog(den) + es * es * rden);
  float zn = -0.5f * (LOG2PI_F - flog(la) + etan * etan * var_n);
  return zeta1 + zeta2 - zm - zn;
}

__device__ __forceinline__ void step_fn(const Vals& cur, float& mu_p, float& var_p,
                                        float* __restrict__ outp) {
  float vsum = var_p + cur.svar;
  float rv = frcp(vsum);
  float logv = flog(vsum);
  float dmu = mu_p - cur.smu;
  float sc = -0.5f * (LOG2PI_F + logv + dmu * dmu * rv);
  float mu_c = (mu_p * cur.svar + cur.smu * var_p) * rv;
  float var_c = vsum - 0.5f * logv;
  float sp = merge2<false>(cur, mu_c, var_c, mu_p, var_p);
  *outp = sc + sp + cur.tw + cur.sw;
}

#define PF 8   // prefetch ring depth — statically indexed (registers guaranteed)

__global__ __launch_bounds__(256) void scan_kernel(
    const u16* __restrict__ Ch, float* __restrict__ out, float* __restrict__ carry,
    int t0, int TC, int isFirst, int isLast) {
  int ij = blockIdx.y * 256 + threadIdx.x;
  if (ij >= L2Q) return;
  int b = blockIdx.x;
  int j = ij % 51;
  const u16* base = Ch + (size_t)b * TC * NPAD;   // chunk-local rows
  float* outb = out + (size_t)b * TQ * L2Q + ij;
  float mu_p, var_p;
  int tfirst;
  if (isFirst) {
    Raw r0 = ldraw(base, ij, j);
    Raw r1 = ldraw(base + NPAD, ij, j);
    Vals v0 = cvtvals(r0);
    Vals v1 = cvtvals(r1);
    float mu_c, var_c;
    float sc0 = merge2<true>(v0, v0.smu, v0.svar, mu_c, var_c);
    float sp0 = merge2<false>(v1, mu_c, var_c, mu_p, var_p);
    outb[0] = sc0 + sp0 + v0.tw + v0.sw;
    tfirst = 1;
  } else {
    mu_p = carry[b * L2Q + ij];
    var_p = carry[BQ * L2Q + b * L2Q + ij];
    tfirst = t0;
  }
  int tend = t0 + TC;
  Raw ring[PF];
#pragma unroll
  for (int p = 0; p < PF; ++p) {
    int t = tfirst + p;
    if (t < tend) ring[p] = ldraw(base + (size_t)(t - t0) * NPAD, ij, j);
  }
  int t = tfirst;
#pragma unroll 1
  while (t + PF <= tend) {
#pragma unroll
    for (int p = 0; p < PF; ++p) {
      Raw cr = ring[p];
      int tp = t + PF;
      if (tp < tend) ring[p] = ldraw(base + (size_t)(tp - t0) * NPAD, ij, j);
      Vals cur = cvtvals(cr);
      step_fn(cur, mu_p, var_p, outb + (size_t)t * L2Q);
      ++t;
    }
  }
#pragma unroll
  for (int p = 0; p < PF; ++p) {
    if (t < tend) {
      Vals cur = cvtvals(ring[p]);
      step_fn(cur, mu_p, var_p, outb + (size_t)t * L2Q);
      ++t;
    }
  }
  if (!isLast) {
    carry[b * L2Q + ij] = mu_p;
    carry[BQ * L2Q + b * L2Q + ij] = var_p;
  }
}

// ---------------------------------------------------------------- launch
extern "C" void kernel_launch(void* const* d_in, const int* in_sizes, int n_in,
                              void* d_out, int out_size, void* d_ws, size_t ws_size,
                              hipStream_t stream) {
  (void)in_sizes; (void)n_in; (void)out_size;
  const float* x      = (const float*)d_in[0];
  const float* Ws_w   = (const float*)d_in[1];
  const float* bs_w   = (const float*)d_in[2];
  const float* Ws_mu  = (const float*)d_in[3];
  const float* bs_mu  = (const float*)d_in[4];
  const float* Ws_var = (const float*)d_in[5];
  const float* bs_var = (const float*)d_in[6];
  const float* Wt_w   = (const float*)d_in[7];
  const float* bt_w   = (const float*)d_in[8];
  const float* Wt_mu  = (const float*)d_in[9];
  const float* bt_mu  = (const float*)d_in[10];
  const float* Wt_var = (const float*)d_in[11];
  const float* bt_var = (const float*)d_in[12];
  float* out = (float*)d_out;

  char* ws = (char*)d_ws;
  const size_t szA = (size_t)4096 * KQ * 2;          // 12,582,912 (256-aligned)
  const size_t szB = (size_t)NPAD * KQ * 2;          // 48,758,784 (256-aligned)
  const size_t szCar = ((size_t)BQ * L2Q * 2 * 4 + 255) & ~(size_t)255;
  u16* Abf = (u16*)ws;
  u16* BTb = (u16*)(ws + szA);
  float* carry = (float*)(ws + szA + szB);
  size_t off0 = szA + szB + szCar;

  // chunk T so the fp16 C buffer fits in ws (TC=256 needs ~192 MB total)
  int TC = 256;
  while (TC > 8 && off0 + (size_t)BQ * TC * NPAD * 2 > ws_size) TC >>= 1;
  __half* Ch = (__half*)(ws + off0);
  int lgTC = 31 - __builtin_clz((unsigned)TC);
  int nch = TQ / TC;
  int nmt = (BQ * TC) / 128;                 // mtiles per chunk (power of 2)
  int lg_nmt = 31 - __builtin_clz((unsigned)nmt);

  build_a_kernel<<<dim3((4096 * 512) / 256), dim3(256), 0, stream>>>(x, Abf, TC, lgTC, nmt);
  build_b_kernel<<<dim3(NPAD / 256, DQ / 8), dim3(256), 0, stream>>>(
      Ws_w, Ws_mu, Ws_var, Wt_w, Wt_mu, Wt_var, BTb);
  for (int c = 0; c < nch; ++c) {
    int t0 = c * TC;
    gemm_kernel<<<dim3(128 * nmt), dim3(256), 0, stream>>>(
        Abf, BTb, Ch, bs_w, bs_mu, bs_var, bt_w, bt_mu, bt_var, c * nmt, lg_nmt);
    scan_kernel<<<dim3(BQ, (L2Q + 255) / 256), dim3(256), 0, stream>>>(
        (const u16*)Ch, out, carry, t0, TC, c == 0 ? 1 : 0, c == nch - 1 ? 1 : 0);
  }
}

// Round 8
// 449.294 us; speedup vs baseline: 2.0586x; 1.5272x over previous
//
#include <hip/hip_runtime.h>
#include <hip/hip_fp16.h>
#include <stdint.h>

#define AS1 __attribute__((address_space(1)))
#define AS3 __attribute__((address_space(3)))

typedef unsigned short u16;
typedef __attribute__((ext_vector_type(8))) short short8;
typedef __attribute__((ext_vector_type(4))) float f32x4;
typedef __attribute__((ext_vector_type(3))) uint32_t u32x3;

#define LOG2PI_F 1.8378770664093453f

// problem constants
#define BQ   16
#define TQ   256
#define DQ   512
#define LQ   51
#define L2Q  2601
#define KQ   1536     // 3*512 (split-bf16: [xh, xl, xh] . [Wh; Wh; Wl])
#define NCOL   15759
#define NPAD   15872  // 124*128
// tiled operand layout (= LDS staging order): [tile][c8(0..191)][row(0..127)][8 u16]
#define TILE_U16  196608
#define TILE_U4   24576
// permuted column layout (baked into B^T row order); ALL raw (bias/exp in scan):
//   col < 15606 : 6*ij + {0:tw, 1:m0, 2:m1, 3:d0raw, 4:ofacraw(=sum of offdiag), 5:d1raw}
//   s-blocks    : sw_raw @ SB0+j, smu_raw @ SB1+j, svar_raw @ SB2+j   (j<51)
#define NSTR 15606
#define SB0  15616
#define SB1  15680
#define SB2  15744
#define SWP  156    // scan LDS s-window pitch (floats)

__device__ __forceinline__ u16 f2bf(float f) {
  uint32_t u = __float_as_uint(f);
  u += 0x7fffu + ((u >> 16) & 1u);   // RNE
  return (u16)(u >> 16);
}
__device__ __forceinline__ float bf2f(u16 h) {
  return __uint_as_float((uint32_t)h << 16);
}
__device__ __forceinline__ float frcp(float x) { return __builtin_amdgcn_rcpf(x); }
__device__ __forceinline__ float flog(float x) { return __builtin_amdgcn_logf(x) * 0.6931471805599453f; }
__device__ __forceinline__ float h2f(u16 bits) {
  union { u16 u; __half h; } cv; cv.u = bits;
  return __half2float(cv.h);
}
__device__ __forceinline__ float2 cvth2(uint32_t w) {
  return __half22float2(*(const __half2*)&w);
}

// ---------------------------------------------------------------- build A (tiled)
__global__ __launch_bounds__(256) void build_a_kernel(const float* __restrict__ x,
                                                      u16* __restrict__ A,
                                                      int TC, int lgTC, int nmt) {
  int idx = blockIdx.x * 256 + threadIdx.x;   // exactly 4096*512
  int m = idx >> 9;
  int k = idx & 511;
  float v = x[idx];
  u16 h = f2bf(v);
  u16 l = f2bf(v - bf2f(h));
  int b = m >> 8, t = m & 255;
  int c = t >> lgTC;                 // chunk
  int tloc = t & (TC - 1);
  int mloc = b * TC + tloc;          // chunk-local row
  int mt = mloc >> 7, r = mloc & 127;
  u16* tile = A + (size_t)(c * nmt + mt) * TILE_U16 + r * 8;
  int c8 = k >> 3, e = k & 7;
  tile[(size_t)c8 * 1024 + e] = h;
  tile[(size_t)(64 + c8) * 1024 + e] = l;
  tile[(size_t)(128 + c8) * 1024 + e] = h;
}

// ---------------------------------------------------------------- build B^T (tiled)
__global__ __launch_bounds__(256) void build_b_kernel(
    const float* __restrict__ Ws_w, const float* __restrict__ Ws_mu,
    const float* __restrict__ Ws_var, const float* __restrict__ Wt_w,
    const float* __restrict__ Wt_mu, const float* __restrict__ Wt_var,
    u16* __restrict__ BT) {
  int n = blockIdx.x * 256 + threadIdx.x;
  if (n >= NPAD) return;
  const float* src = nullptr;
  int c0 = 0, stride = 0, two = 0;
  if (n < NSTR) {
    int ij = (int)((unsigned)n / 6u);
    int r = n - 6 * ij;
    switch (r) {
      case 0: src = Wt_w;   stride = L2Q;     c0 = ij;         break;
      case 1: src = Wt_mu;  stride = 2 * L2Q; c0 = 2 * ij;     break;
      case 2: src = Wt_mu;  stride = 2 * L2Q; c0 = 2 * ij + 1; break;
      case 3: src = Wt_var; stride = 4 * L2Q; c0 = 4 * ij;     break;
      case 4: src = Wt_var; stride = 4 * L2Q; c0 = 4 * ij + 1; two = 1; break;
      default: src = Wt_var; stride = 4 * L2Q; c0 = 4 * ij + 3; break;
    }
  } else if (n >= SB0 && n < SB0 + LQ) { src = Ws_w;   stride = LQ; c0 = n - SB0; }
  else if (n >= SB1 && n < SB1 + LQ)   { src = Ws_mu;  stride = LQ; c0 = n - SB1; }
  else if (n >= SB2 && n < SB2 + LQ)   { src = Ws_var; stride = LQ; c0 = n - SB2; }
  int kb = blockIdx.y * 8;
  union { u16 u[8]; uint4 v; } H, L;
#pragma unroll
  for (int t = 0; t < 8; ++t) {
    float w = 0.f;
    if (src) {
      const float* p = src + (size_t)(kb + t) * stride + c0;
      w = p[0];
      if (two) w += p[1];
    }
    u16 h = f2bf(w);
    H.u[t] = h;
    L.u[t] = f2bf(w - bf2f(h));
  }
  int nt = n >> 7, col = n & 127;
  uint4* tb = (uint4*)BT + (size_t)nt * TILE_U4 + col;
  int c8 = kb >> 3;
  tb[(size_t)c8 * 128] = H.v;
  tb[(size_t)(64 + c8) * 128] = H.v;
  tb[(size_t)(128 + c8) * 128] = L.v;
}

// ---------------------------------------------------------------- GEMM
// Per-XCD order: mset(8 mtiles) -> ntile -> msub: A working set 3.1MB stays
// L2-resident across the 16 ntiles of a set; B-slices stream (L2-hot per cohort).
__global__ __launch_bounds__(256, 2) void gemm_kernel(
    const u16* __restrict__ A, const u16* __restrict__ BT,
    __half* __restrict__ C, int tile0, int lg_nmt) {
  const int lin = blockIdx.x;
  const int xcd = lin & 7;
  const int s = lin >> 3;
  const int mb = lg_nmt < 3 ? lg_nmt : 3;
  const int msub = s & ((1 << mb) - 1);
  const int ntsel = (s >> mb) & 15;
  const int mset = s >> (mb + 4);
  const int mtile = (mset << mb) + msub;
  const int ntile = (ntsel << 3) + xcd;
  if (ntile >= 124) return;

  __shared__ uint4 sA[1024];   // 16B units: [kc(0..7)][row(0..127)]
  __shared__ uint4 sB[1024];
  const int tid = threadIdx.x;
  const int lane = tid & 63;
  const int wave = tid >> 6;
  const int wm = (wave >> 1) * 64;
  const int wn = (wave & 1) * 64;
  const int q4 = lane >> 4;
  const int c16 = lane & 15;

  const uint4* At = (const uint4*)A + (size_t)(tile0 + mtile) * TILE_U4;
  const uint4* Bt = (const uint4*)BT + (size_t)ntile * TILE_U4;

  f32x4 acc[4][4];
#pragma unroll
  for (int a_ = 0; a_ < 4; ++a_)
#pragma unroll
    for (int b_ = 0; b_ < 4; ++b_) acc[a_][b_] = (f32x4){0.f, 0.f, 0.f, 0.f};

  AS3 uint4* sA3 = (AS3 uint4*)sA;
  AS3 uint4* sB3 = (AS3 uint4*)sB;

  for (int kwin = 0; kwin < 24; ++kwin) {
    const uint4* wa = At + kwin * 1024;
    const uint4* wb = Bt + kwin * 1024;
#pragma unroll
    for (int ss = 0; ss < 4; ++ss) {
      int jj = wave * 4 + ss;
      __builtin_amdgcn_global_load_lds((const AS1 void*)(wa + jj * 64 + lane),
                                       (AS3 void*)(sA3 + jj * 64), 16, 0, 0);
      __builtin_amdgcn_global_load_lds((const AS1 void*)(wb + jj * 64 + lane),
                                       (AS3 void*)(sB3 + jj * 64), 16, 0, 0);
    }
    __syncthreads();
#pragma unroll
    for (int ks = 0; ks < 2; ++ks) {
      int kc = ks * 4 + q4;
      short8 af[4], bfv[4];
#pragma unroll
      for (int f = 0; f < 4; ++f) {
        af[f]  = *(const short8*)&sA[kc * 128 + wm + f * 16 + c16];
        bfv[f] = *(const short8*)&sB[kc * 128 + wn + f * 16 + c16];
      }
#pragma unroll
      for (int fr = 0; fr < 4; ++fr)
#pragma unroll
        for (int fc = 0; fc < 4; ++fc)
          acc[fr][fc] = __builtin_amdgcn_mfma_f32_16x16x32_bf16(af[fr], bfv[fc],
                                                                acc[fr][fc], 0, 0, 0);
    }
    __syncthreads();
  }

  // epilogue: raw fp16 store (no xform, no divergence)
#pragma unroll
  for (int fc = 0; fc < 4; ++fc) {
    int col = ntile * 128 + wn + fc * 16 + c16;
#pragma unroll
    for (int fr = 0; fr < 4; ++fr) {
      int grow = mtile * 128 + wm + fr * 16 + q4 * 4;
#pragma unroll
      for (int i = 0; i < 4; ++i)
        C[(size_t)(grow + i) * NPAD + col] = __float2half(acc[fr][fc][i]);
    }
  }
}

// ---------------------------------------------------------------- scan
struct Vals { float sw, smu, svar, tw, m0, m1, d0, ofac, d1; };

template <bool CHILD>
__device__ __forceinline__ float merge2(const Vals& v, float nmu, float nvar,
                                        float& mu_n, float& var_n) {
  float off = v.ofac * __builtin_amdgcn_sqrtf(v.d0 * v.d1);
  float det = fmaf(v.d0, v.d1, -off * off);
  float inv = frcp(det);
  float a = v.d1 * inv, bo = -off * inv, d = v.d0 * inv;
  float e0 = a * v.m0 + bo * v.m1;
  float e1 = bo * v.m0 + d * v.m1;
  float quad1 = e0 * e0 * v.d0 + 2.f * e0 * e1 * off + e1 * e1 * v.d1;
  float zeta1 = -0.5f * (2.f * LOG2PI_F + flog(det) + quad1);
  float l2 = frcp(nvar);
  float eta2 = nmu * l2;
  float zeta2 = -0.5f * (LOG2PI_F + flog(nvar) + nmu * eta2);
  float den, keep, es, la;
  if (CHILD) { den = d + l2; keep = e0; es = e1 + eta2; }
  else       { den = a + l2; keep = e1; es = e0 + eta2; }
  float rden = frcp(den);
  if (CHILD) la = a - bo * bo * rden;
  else       la = d - bo * bo * rden;
  float etan = keep - bo * rden * es;
  var_n = frcp(la);
  mu_n = var_n * etan;
  float zm = -0.5f * (LOG2PI_F - flog(den) + es * es * rden);
  float zn = -0.5f * (LOG2PI_F - flog(la) + etan * etan * var_n);
  return zeta1 + zeta2 - zm - zn;
}

__device__ __forceinline__ Vals decode_t(u32x3 cr, float btw, float btm0, float btm1,
                                         float bv0, float bv12, float bv3) {
  float2 p0 = cvth2(cr.x);
  float2 p1 = cvth2(cr.y);
  float2 p2 = cvth2(cr.z);
  Vals cur;
  cur.tw = p0.x + btw;
  cur.m0 = p0.y + btm0;
  cur.m1 = p1.x + btm1;
  cur.d0 = __expf(fminf(fmaxf(p1.y + bv0, -1.f), 1.f));
  float u = fminf(fmaxf(p2.x + bv12, -20.f), 20.f);
  float ex = __expf(u);
  cur.ofac = 0.9f * (ex - 1.f) * frcp(ex + 1.f);
  cur.d1 = __expf(fminf(fmaxf(p2.y + bv3, -1.f), 1.f));
  cur.sw = 0.f; cur.smu = 0.f; cur.svar = 1.f;
  return cur;
}

__global__ __launch_bounds__(256) void scan_kernel(
    const u16* __restrict__ Ch, float* __restrict__ out, float* __restrict__ carry,
    const float* __restrict__ bs_w, const float* __restrict__ bs_mu,
    const float* __restrict__ bs_var, const float* __restrict__ bt_w,
    const float* __restrict__ bt_mu, const float* __restrict__ bt_var,
    int t0, int TC, int isFirst, int isLast) {
  __shared__ float slds[16 * SWP];
  int tid = threadIdx.x;
  int ij0 = blockIdx.y * 256 + tid;
  int valid = ij0 < L2Q;
  int ij = valid ? ij0 : L2Q - 1;
  int b = blockIdx.x;
  int j = (int)((unsigned)ij % 51u);
  const u16* base = Ch + (size_t)b * TC * NPAD;
  float* outb = out + (size_t)b * TQ * L2Q + ij0;
  // per-thread t-field biases
  float btw = bt_w[ij];
  float btm0 = bt_mu[2 * ij], btm1 = bt_mu[2 * ij + 1];
  float bv0 = bt_var[4 * ij];
  float bv12 = bt_var[4 * ij + 1] + bt_var[4 * ij + 2];
  float bv3 = bt_var[4 * ij + 3];
  float mu_p = 0.f, var_p = 1.f;
  if (!isFirst) {
    mu_p = carry[b * L2Q + ij];
    var_p = carry[BQ * L2Q + b * L2Q + ij];
  }
  // ring init: window 0 (dt = 0..15); 16-deep static register ring
  u32x3 ring[16];
#pragma unroll
  for (int p = 0; p < 16; ++p)
    ring[p] = *(const u32x3*)(base + (size_t)p * NPAD + 6 * ij);

  int nwin = TC >> 4;
#pragma unroll 1
  for (int w = 0; w < nwin; ++w) {
    __syncthreads();
    // stage s-window (rows w*16..+15) into LDS with bias (+exp for svar)
    for (int idx = tid; idx < 16 * 153; idx += 256) {
      int tt = (int)((unsigned)idx / 153u);
      int f = idx - tt * 153;
      int col; float bias; int cls = 0;
      if (f < 51)       { col = SB0 + f;         bias = bs_w[f]; }
      else if (f < 102) { col = SB1 + (f - 51);  bias = bs_mu[f - 51]; }
      else              { col = SB2 + (f - 102); bias = bs_var[f - 102]; cls = 1; }
      float rv = h2f(base[(size_t)(w * 16 + tt) * NPAD + col]) + bias;
      if (cls) rv = __expf(fminf(fmaxf(rv, -1.f), 1.f));
      slds[tt * SWP + f] = rv;
    }
    __syncthreads();
#pragma unroll
    for (int tt = 0; tt < 16; ++tt) {
      int dt = w * 16 + tt;
      int t = t0 + dt;
      u32x3 cr = ring[tt];
      int dtn = dt + 16;
      if (dtn > TC - 1) dtn = TC - 1;          // clamp (harmless extra read)
      u32x3 nx = *(const u32x3*)(base + (size_t)dtn * NPAD + 6 * ij);
      Vals cur = decode_t(cr, btw, btm0, btm1, bv0, bv12, bv3);
      cur.sw   = slds[tt * SWP + j];
      cur.smu  = slds[tt * SWP + 51 + j];
      cur.svar = slds[tt * SWP + 102 + j];
      if (tt == 0 && w == 0 && isFirst) {
        // t=0: child-merge with s0, then parent-merge with t-struct of row 1
        float mu_c, var_c;
        float sc0 = merge2<true>(cur, cur.smu, cur.svar, mu_c, var_c);
        Vals v1 = decode_t(ring[1], btw, btm0, btm1, bv0, bv12, bv3);
        float sp0 = merge2<false>(v1, mu_c, var_c, mu_p, var_p);
        if (valid) outb[0] = sc0 + sp0 + cur.tw + cur.sw;
      } else {
        float vsum = var_p + cur.svar;
        float rv = frcp(vsum);
        float logv = flog(vsum);
        float dmu = mu_p - cur.smu;
        float sc = -0.5f * (LOG2PI_F + logv + dmu * dmu * rv);
        float mu_c = (mu_p * cur.svar + cur.smu * var_p) * rv;
        float var_c = vsum - 0.5f * logv;
        float sp = merge2<false>(cur, mu_c, var_c, mu_p, var_p);
        if (valid) outb[(size_t)t * L2Q] = sc + sp + cur.tw + cur.sw;
      }
      ring[tt] = nx;
    }
  }
  if (!isLast && valid) {
    carry[b * L2Q + ij] = mu_p;
    carry[BQ * L2Q + b * L2Q + ij] = var_p;
  }
}

// ---------------------------------------------------------------- launch
extern "C" void kernel_launch(void* const* d_in, const int* in_sizes, int n_in,
                              void* d_out, int out_size, void* d_ws, size_t ws_size,
                              hipStream_t stream) {
  (void)in_sizes; (void)n_in; (void)out_size;
  const float* x      = (const float*)d_in[0];
  const float* Ws_w   = (const float*)d_in[1];
  const float* bs_w   = (const float*)d_in[2];
  const float* Ws_mu  = (const float*)d_in[3];
  const float* bs_mu  = (const float*)d_in[4];
  const float* Ws_var = (const float*)d_in[5];
  const float* bs_var = (const float*)d_in[6];
  const float* Wt_w   = (const float*)d_in[7];
  const float* bt_w   = (const float*)d_in[8];
  const float* Wt_mu  = (const float*)d_in[9];
  const float* bt_mu  = (const float*)d_in[10];
  const float* Wt_var = (const float*)d_in[11];
  const float* bt_var = (const float*)d_in[12];
  float* out = (float*)d_out;

  char* ws = (char*)d_ws;
  const size_t szA = (size_t)4096 * KQ * 2;
  const size_t szB = (size_t)NPAD * KQ * 2;
  const size_t szCar = ((size_t)BQ * L2Q * 2 * 4 + 255) & ~(size_t)255;
  u16* Abf = (u16*)ws;
  u16* BTb = (u16*)(ws + szA);
  float* carry = (float*)(ws + szA + szB);
  size_t off0 = szA + szB + szCar;

  // chunk T so the fp16 C buffer fits in ws (TC=256 needs ~192 MB total)
  int TC = 256;
  while (TC > 16 && off0 + (size_t)BQ * TC * NPAD * 2 > ws_size) TC >>= 1;
  __half* Ch = (__half*)(ws + off0);
  int lgTC = 31 - __builtin_clz((unsigned)TC);
  int nch = TQ / TC;
  int nmt = (BQ * TC) / 128;
  int lg_nmt = 31 - __builtin_clz((unsigned)nmt);

  build_a_kernel<<<dim3((4096 * 512) / 256), dim3(256), 0, stream>>>(x, Abf, TC, lgTC, nmt);
  build_b_kernel<<<dim3(NPAD / 256, DQ / 8), dim3(256), 0, stream>>>(
      Ws_w, Ws_mu, Ws_var, Wt_w, Wt_mu, Wt_var, BTb);
  for (int c = 0; c < nch; ++c) {
    int t0 = c * TC;
    gemm_kernel<<<dim3(128 * nmt), dim3(256), 0, stream>>>(
        Abf, BTb, Ch, c * nmt, lg_nmt);
    scan_kernel<<<dim3(BQ, (L2Q + 255) / 256), dim3(256), 0, stream>>>(
        (const u16*)Ch, out, carry, bs_w, bs_mu, bs_var, bt_w, bt_mu, bt_var,
        t0, TC, c == 0 ? 1 : 0, c == nch - 1 ? 1 : 0);
  }
}